// Round 1
// 451.287 us; speedup vs baseline: 1.0069x; 1.0069x over previous
//
#include <hip/hip_runtime.h>
#include <hip/hip_bf16.h>
#include <stdint.h>

#define Bsz 4096
#define Csz 10000
#define Dsz 256
#define BM 128
#define BN 128
#define BK 32
#define KST 40   // fallback-path LDS row stride (old kernel)

#define NCOLB 79                 // ceil(10000/128)
#define NROWB 32                 // 4096/128
#define NWG   (NCOLB * NROWB)    // 2528 = 8 * 316 exactly -> simple bijective XCD swizzle
#define CPX   (NWG / 8)          // 316 blocks per XCD chunk

typedef __attribute__((ext_vector_type(8))) __bf16 bf16x8;  // 4 VGPRs, matches mfma builtin
typedef __attribute__((ext_vector_type(4))) float f32x4;

typedef const __attribute__((address_space(1))) void GmemV;
typedef __attribute__((address_space(3))) void LdsV;

__device__ __forceinline__ unsigned int f2bf(float x) {
    // round-to-nearest-even fp32 -> bf16 (inputs are finite normals)
    unsigned int u = __float_as_uint(x);
    return (u + 0x7fffu + ((u >> 16) & 1u)) >> 16;
}
__device__ __forceinline__ unsigned int pack2(float a, float b) {
    return f2bf(a) | (f2bf(b) << 16);
}

// ---- kernel 1 (new): f_sq/c_sq AND one-time bf16 conversion of feat+centers into ws ----
// 4 rows/block, 64 lanes/row, float4 in -> uint2 (4 bf16) out; shuffle-reduce for sq-norm.
__global__ __launch_bounds__(256) void prep_kernel(
        const float* __restrict__ feat, const float* __restrict__ centers,
        unsigned short* __restrict__ featb, unsigned short* __restrict__ centb,
        float* __restrict__ fsq, float* __restrict__ csq, float* __restrict__ like_out) {
    if (blockIdx.x == 0 && threadIdx.x == 0) *like_out = 0.f;
    int row  = blockIdx.x * 4 + (threadIdx.x >> 6);
    int lane = threadIdx.x & 63;
    if (row >= Bsz + Csz) return;
    const float* src;
    unsigned short* dst;
    float* sq;
    if (row < Bsz) {
        src = feat + (size_t)row * Dsz;
        dst = featb + (size_t)row * Dsz;
        sq  = fsq + row;
    } else {
        int r = row - Bsz;
        src = centers + (size_t)r * Dsz;
        dst = centb + (size_t)r * Dsz;
        sq  = csq + r;
    }
    float4 v = *(const float4*)(src + lane * 4);
    *(uint2*)(dst + lane * 4) = make_uint2(pack2(v.x, v.y), pack2(v.z, v.w));
    float s = v.x * v.x + v.y * v.y + v.z * v.z + v.w * v.w;
    #pragma unroll
    for (int o = 32; o > 0; o >>= 1) s += __shfl_down(s, o);
    if (lane == 0) *sq = s;
}

// ---- kernel 2: likelihood = sum_b ||feat[b]-centers[label[b]]||^2 / (2B) ----
__global__ __launch_bounds__(256) void like_kernel(
        const float* __restrict__ feat, const float* __restrict__ centers,
        const int* __restrict__ label, float* __restrict__ like_out) {
    int row  = blockIdx.x * 4 + (threadIdx.x >> 6);
    int lane = threadIdx.x & 63;
    int lb = label[row];
    float4 f = *(const float4*)(feat + (size_t)row * Dsz + lane * 4);
    float4 c = *(const float4*)(centers + (size_t)lb * Dsz + lane * 4);
    float dx = f.x - c.x, dy = f.y - c.y, dz = f.z - c.z, dw = f.w - c.w;
    float s = dx * dx + dy * dy + dz * dz + dw * dw;
    #pragma unroll
    for (int o = 32; o > 0; o >>= 1) s += __shfl_down(s, o);
    if (lane == 0) atomicAdd(like_out, s * (1.0f / (2.0f * Bsz)));
}

// ---- kernel 3 (new): m97-structure GEMM on pre-converted bf16 ----
// Linear 128x32 bf16 LDS tiles (8 KB each), staged with global_load_lds width=16
// (wave-uniform LDS base + lane*16; 2 issues/wave per tile). No VALU pack, no
// ds_write. XCD-chunked bijective swizzle, column-major chunks: per-XCD working
// set = full bf16 feat (2 MB) + ~10 centers slices (0.65 MB) < 4 MB L2.
__global__ __launch_bounds__(256) void lgm_gemm_bf_kernel(
        const unsigned short* __restrict__ featb, const unsigned short* __restrict__ centb,
        const int* __restrict__ label, const float* __restrict__ fsq,
        const float* __restrict__ csq, float* __restrict__ out) {
    __shared__ unsigned short As[BM * BK];   // 8 KB, LINEAR (global_load_lds requirement)
    __shared__ unsigned short Bs[BN * BK];   // 8 KB
    __shared__ float Fs[BM];
    __shared__ float Cq[BN];
    __shared__ int   Lb[BM];

    // bijective XCD swizzle: 2528 = 8*316, chunk c covers logical ids [316c, 316c+316)
    const int bid = blockIdx.x;
    const int wg  = (bid & 7) * CPX + (bid >> 3);
    const int by  = wg & 31;          // row-block (feat)   — fastest within chunk
    const int bx  = wg >> 5;          // col-block (centers)
    const int rowBase = by * BM;
    const int colBase = bx * BN;

    const int tid = threadIdx.x;
    if (tid < 128) {
        Fs[tid] = fsq[rowBase + tid];
        Lb[tid] = label[rowBase + tid];
        int c = colBase + tid;
        Cq[tid] = (c < Csz) ? csq[c] : 0.f;
    }

    const int lane = tid & 63;
    const int wv   = tid >> 6;
    const int wr   = (wv >> 1) * 64;
    const int wc   = (wv & 1) * 64;
    const int quad = lane >> 4;
    const int l15  = lane & 15;

    // staging geometry: wave wv fills LDS bytes [2048*wv, 2048*wv+2048) in 2 issues.
    // lane fills byte base+16*lane -> LDS row = 32*wv + 16*r + (lane>>2), elem (lane&3)*8
    const int srow = wv * 32 + (lane >> 2);
    const int scol = (lane & 3) * 8;

    f32x4 acc[4][4];
    #pragma unroll
    for (int i = 0; i < 4; ++i)
        #pragma unroll
        for (int j = 0; j < 4; ++j)
            acc[i][j] = (f32x4){0.f, 0.f, 0.f, 0.f};

    for (int k0 = 0; k0 < Dsz; k0 += BK) {
        __syncthreads();  // previous iter's LDS reads done before overwrite
        #pragma unroll
        for (int r = 0; r < 2; ++r) {
            const unsigned short* g =
                featb + (size_t)(rowBase + srow + r * 16) * Dsz + k0 + scol;
            __builtin_amdgcn_global_load_lds((GmemV*)g,
                (LdsV*)(As + wv * 1024 + r * 512), 16, 0, 0);
        }
        #pragma unroll
        for (int r = 0; r < 2; ++r) {
            int crow = colBase + srow + r * 16;
            if (crow >= Csz) crow = Csz - 1;   // clamp: stores masked later
            const unsigned short* g = centb + (size_t)crow * Dsz + k0 + scol;
            __builtin_amdgcn_global_load_lds((GmemV*)g,
                (LdsV*)(Bs + wv * 1024 + r * 512), 16, 0, 0);
        }
        __syncthreads();  // compiler emits vmcnt(0) drain here (m97 structure)

        bf16x8 af[4], bfr[4];
        #pragma unroll
        for (int mi = 0; mi < 4; ++mi)
            af[mi] = *(const bf16x8*)(As + (wr + mi * 16 + l15) * BK + quad * 8);
        #pragma unroll
        for (int ni = 0; ni < 4; ++ni)
            bfr[ni] = *(const bf16x8*)(Bs + (wc + ni * 16 + l15) * BK + quad * 8);
        #pragma unroll
        for (int mi = 0; mi < 4; ++mi)
            #pragma unroll
            for (int ni = 0; ni < 4; ++ni)
                acc[mi][ni] = __builtin_amdgcn_mfma_f32_16x16x32_bf16(
                    af[mi], bfr[ni], acc[mi][ni], 0, 0, 0);
    }

    // epilogue: C/D layout col=lane&15, row=quad*4+reg (verified m89/m91)
    float* outL = out;
    float* outM = out + (size_t)Bsz * Csz;
    #pragma unroll
    for (int mi = 0; mi < 4; ++mi) {
        const int rT0 = wr + mi * 16 + quad * 4;
        float fr[4]; int lb[4]; int gr[4];
        #pragma unroll
        for (int r = 0; r < 4; ++r) {
            fr[r] = Fs[rT0 + r];
            lb[r] = Lb[rT0 + r];
            gr[r] = rowBase + rT0 + r;
        }
        #pragma unroll
        for (int ni = 0; ni < 4; ++ni) {
            const int cT = wc + ni * 16 + l15;
            const int gc = colBase + cT;
            if (gc >= Csz) continue;
            const float cs = Cq[cT];
            f32x4 a = acc[mi][ni];
            #pragma unroll
            for (int r = 0; r < 4; ++r) {
                float logit = a[r] - 0.5f * (fr[r] + cs);
                float marg  = (gc == lb[r]) ? logit * 1.1f : logit;
                size_t off = (size_t)gr[r] * Csz + gc;
                outL[off] = logit;
                outM[off] = marg;
            }
        }
    }
}

// ================= fallback path (ws too small): previous verified kernels =================
__global__ __launch_bounds__(256) void sqnorm_kernel(
        const float* __restrict__ feat, const float* __restrict__ centers,
        float* __restrict__ ws, float* __restrict__ like_out) {
    if (blockIdx.x == 0 && threadIdx.x == 0) *like_out = 0.f;
    int row  = blockIdx.x * 4 + (threadIdx.x >> 6);
    int lane = threadIdx.x & 63;
    if (row >= Bsz + Csz) return;
    const float* src = (row < Bsz) ? feat + (size_t)row * Dsz
                                   : centers + (size_t)(row - Bsz) * Dsz;
    float4 v = *(const float4*)(src + lane * 4);
    float s = v.x * v.x + v.y * v.y + v.z * v.z + v.w * v.w;
    #pragma unroll
    for (int o = 32; o > 0; o >>= 1) s += __shfl_down(s, o);
    if (lane == 0) ws[row] = s;
}

__global__ __launch_bounds__(256) void lgm_gemm_kernel(
        const float* __restrict__ feat, const float* __restrict__ centers,
        const int* __restrict__ label, const float* __restrict__ fsq,
        const float* __restrict__ csq, float* __restrict__ out) {
    __shared__ unsigned short As[BM * KST];
    __shared__ unsigned short Bs[BN * KST];
    __shared__ float Fs[BM];
    __shared__ float Cq[BN];
    __shared__ int   Lb[BM];

    const int tid     = threadIdx.x;
    const int rowBase = blockIdx.y * BM;
    const int colBase = blockIdx.x * BN;

    if (tid < 128) {
        Fs[tid] = fsq[rowBase + tid];
        Lb[tid] = label[rowBase + tid];
        int c = colBase + tid;
        Cq[tid] = (c < Csz) ? csq[c] : 0.f;
    }

    const int lane = tid & 63;
    const int wv   = tid >> 6;
    const int wr   = (wv >> 1) * 64;
    const int wc   = (wv & 1) * 64;
    const int quad = lane >> 4;
    const int l15  = lane & 15;

    f32x4 acc[4][4];
    #pragma unroll
    for (int i = 0; i < 4; ++i)
        #pragma unroll
        for (int j = 0; j < 4; ++j)
            acc[i][j] = (f32x4){0.f, 0.f, 0.f, 0.f};

    const int sr = tid >> 3;
    const int sf = tid & 7;

    for (int k0 = 0; k0 < Dsz; k0 += BK) {
        __syncthreads();
        #pragma unroll
        for (int rr = 0; rr < BM; rr += 32) {
            int r = sr + rr;
            float4 v = *(const float4*)(feat + (size_t)(rowBase + r) * Dsz + k0 + sf * 4);
            *(uint2*)(As + r * KST + sf * 4) = make_uint2(pack2(v.x, v.y), pack2(v.z, v.w));
        }
        #pragma unroll
        for (int rr = 0; rr < BN; rr += 32) {
            int r = sr + rr;
            int crow = colBase + r;
            if (crow >= Csz) crow = Csz - 1;
            float4 v = *(const float4*)(centers + (size_t)crow * Dsz + k0 + sf * 4);
            *(uint2*)(Bs + r * KST + sf * 4) = make_uint2(pack2(v.x, v.y), pack2(v.z, v.w));
        }
        __syncthreads();

        bf16x8 af[4], bfr[4];
        #pragma unroll
        for (int mi = 0; mi < 4; ++mi)
            af[mi] = *(const bf16x8*)(As + (wr + mi * 16 + l15) * KST + quad * 8);
        #pragma unroll
        for (int ni = 0; ni < 4; ++ni)
            bfr[ni] = *(const bf16x8*)(Bs + (wc + ni * 16 + l15) * KST + quad * 8);
        #pragma unroll
        for (int mi = 0; mi < 4; ++mi)
            #pragma unroll
            for (int ni = 0; ni < 4; ++ni)
                acc[mi][ni] = __builtin_amdgcn_mfma_f32_16x16x32_bf16(
                    af[mi], bfr[ni], acc[mi][ni], 0, 0, 0);
    }

    float* outL = out;
    float* outM = out + (size_t)Bsz * Csz;
    #pragma unroll
    for (int mi = 0; mi < 4; ++mi) {
        const int rT0 = wr + mi * 16 + quad * 4;
        float fr[4]; int lb[4]; int gr[4];
        #pragma unroll
        for (int r = 0; r < 4; ++r) {
            fr[r] = Fs[rT0 + r];
            lb[r] = Lb[rT0 + r];
            gr[r] = rowBase + rT0 + r;
        }
        #pragma unroll
        for (int ni = 0; ni < 4; ++ni) {
            const int cT = wc + ni * 16 + l15;
            const int gc = colBase + cT;
            if (gc >= Csz) continue;
            const float cs = Cq[cT];
            f32x4 a = acc[mi][ni];
            #pragma unroll
            for (int r = 0; r < 4; ++r) {
                float logit = a[r] - 0.5f * (fr[r] + cs);
                float marg  = (gc == lb[r]) ? logit * 1.1f : logit;
                size_t off = (size_t)gr[r] * Csz + gc;
                outL[off] = logit;
                outM[off] = marg;
            }
        }
    }
}

extern "C" void kernel_launch(void* const* d_in, const int* in_sizes, int n_in,
                              void* d_out, int out_size, void* d_ws, size_t ws_size,
                              hipStream_t stream) {
    const float* feat    = (const float*)d_in[0];
    const int*   label   = (const int*)d_in[1];
    const float* centers = (const float*)d_in[2];
    float* out = (float*)d_out;
    float* like_out = out + (size_t)2 * Bsz * Csz;

    const size_t bf_bytes = (size_t)(Bsz + Csz) * Dsz * sizeof(unsigned short); // 7.22 MB
    const size_t ws_need  = bf_bytes + (size_t)(Bsz + Csz) * sizeof(float) + 256;

    if (ws_size >= ws_need) {
        unsigned short* featb = (unsigned short*)d_ws;
        unsigned short* centb = featb + (size_t)Bsz * Dsz;
        float* fsq = (float*)(centb + (size_t)Csz * Dsz);
        float* csq = fsq + Bsz;
        prep_kernel<<<dim3((Bsz + Csz) / 4), 256, 0, stream>>>(
            feat, centers, featb, centb, fsq, csq, like_out);
        like_kernel<<<dim3(Bsz / 4), 256, 0, stream>>>(feat, centers, label, like_out);
        lgm_gemm_bf_kernel<<<dim3(NWG), 256, 0, stream>>>(
            featb, centb, label, fsq, csq, out);
    } else {
        float* fsq = (float*)d_ws;
        float* csq = fsq + Bsz;
        sqnorm_kernel<<<dim3((Bsz + Csz + 3) / 4), 256, 0, stream>>>(feat, centers, fsq, like_out);
        like_kernel<<<dim3(Bsz / 4), 256, 0, stream>>>(feat, centers, label, like_out);
        lgm_gemm_kernel<<<dim3((Csz + BN - 1) / BN, Bsz / BM), 256, 0, stream>>>(
            feat, centers, label, fsq, csq, out);
    }
}

// Round 2
// 445.479 us; speedup vs baseline: 1.0200x; 1.0130x over previous
//
#include <hip/hip_runtime.h>
#include <hip/hip_bf16.h>
#include <stdint.h>

#define Bsz 4096
#define Csz 10000
#define Dsz 256
#define BM 128
#define BN 128
#define BK 32
#define KST 40   // fallback-path LDS row stride (old kernel)

#define NCOLB 79                 // ceil(10000/128)
#define NROWB 32                 // 4096/128
#define NWG   (NCOLB * NROWB)    // 2528 = 8 * 316 exactly -> bijective XCD swizzle
#define CPX   (NWG / 8)          // 316 blocks per XCD chunk

typedef __attribute__((ext_vector_type(8))) __bf16 bf16x8;  // 4 VGPRs, matches mfma builtin
typedef __attribute__((ext_vector_type(4))) float f32x4;

typedef const __attribute__((address_space(1))) void GmemV;
typedef __attribute__((address_space(3))) void LdsV;

__device__ __forceinline__ unsigned int f2bf(float x) {
    unsigned int u = __float_as_uint(x);
    return (u + 0x7fffu + ((u >> 16) & 1u)) >> 16;
}
__device__ __forceinline__ unsigned int pack2(float a, float b) {
    return f2bf(a) | (f2bf(b) << 16);
}

// ---- kernel 1: f_sq/c_sq AND one-time bf16 conversion of feat+centers into ws ----
__global__ __launch_bounds__(256) void prep_kernel(
        const float* __restrict__ feat, const float* __restrict__ centers,
        unsigned short* __restrict__ featb, unsigned short* __restrict__ centb,
        float* __restrict__ fsq, float* __restrict__ csq, float* __restrict__ like_out) {
    if (blockIdx.x == 0 && threadIdx.x == 0) *like_out = 0.f;
    int row  = blockIdx.x * 4 + (threadIdx.x >> 6);
    int lane = threadIdx.x & 63;
    if (row >= Bsz + Csz) return;
    const float* src;
    unsigned short* dst;
    float* sq;
    if (row < Bsz) {
        src = feat + (size_t)row * Dsz;
        dst = featb + (size_t)row * Dsz;
        sq  = fsq + row;
    } else {
        int r = row - Bsz;
        src = centers + (size_t)r * Dsz;
        dst = centb + (size_t)r * Dsz;
        sq  = csq + r;
    }
    float4 v = *(const float4*)(src + lane * 4);
    *(uint2*)(dst + lane * 4) = make_uint2(pack2(v.x, v.y), pack2(v.z, v.w));
    float s = v.x * v.x + v.y * v.y + v.z * v.z + v.w * v.w;
    #pragma unroll
    for (int o = 32; o > 0; o >>= 1) s += __shfl_down(s, o);
    if (lane == 0) *sq = s;
}

// ---- kernel 2: likelihood ----
__global__ __launch_bounds__(256) void like_kernel(
        const float* __restrict__ feat, const float* __restrict__ centers,
        const int* __restrict__ label, float* __restrict__ like_out) {
    int row  = blockIdx.x * 4 + (threadIdx.x >> 6);
    int lane = threadIdx.x & 63;
    int lb = label[row];
    float4 f = *(const float4*)(feat + (size_t)row * Dsz + lane * 4);
    float4 c = *(const float4*)(centers + (size_t)lb * Dsz + lane * 4);
    float dx = f.x - c.x, dy = f.y - c.y, dz = f.z - c.z, dw = f.w - c.w;
    float s = dx * dx + dy * dy + dz * dz + dw * dw;
    #pragma unroll
    for (int o = 32; o > 0; o >>= 1) s += __shfl_down(s, o);
    if (lane == 0) atomicAdd(like_out, s * (1.0f / (2.0f * Bsz)));
}

// ---- kernel 3: bf16 GEMM, 2-phase pipelined, swizzled LDS, full-line epilogue ----
// LDS chunk swizzle (K-loop): 16B chunk (row,q) stored at slot row*4 + (q ^ ((row>>1)&3)).
//   - global_load_lds dest stays LINEAR; the per-lane GLOBAL source picks q = (lane&3)^((lane>>3)&3).
//   - ds_read_b128 uses q' = quad ^ ((l15>>1)&3)  -> uniform 8 lanes per 4-bank group (conflict-free).
// Epilogue: acc -> Ep[32][128] f32 in LDS (4-float-block XOR swizzle (row&7)) -> each wave
//   stores 2 rows x 512 B contiguous dwordx4 (full 128B lines, no partial-line RMW).
__global__ __launch_bounds__(256, 3) void lgm_gemm_bf_kernel(
        const unsigned short* __restrict__ featb, const unsigned short* __restrict__ centb,
        const int* __restrict__ label, const float* __restrict__ fsq,
        const float* __restrict__ csq, float* __restrict__ out) {
    __shared__ __align__(16) unsigned short AB[2][8192];  // [buf][As 4096 | Bs 4096] = 2x16KB
    __shared__ float Fs[BM];
    __shared__ float Cq[BN];
    __shared__ int   Lb[BM];

    const int bid = blockIdx.x;
    const int wg  = (bid & 7) * CPX + (bid >> 3);
    const int by  = wg & 31;          // row-block (feat), fastest within XCD chunk
    const int bx  = wg >> 5;          // col-block (centers)
    const int rowBase = by * BM;
    const int colBase = bx * BN;

    const int tid  = threadIdx.x;
    const int lane = tid & 63;
    const int wv   = tid >> 6;
    const int wr   = (wv >> 1) * 64;
    const int wc   = (wv & 1) * 64;
    const int quad = lane >> 4;
    const int l15  = lane & 15;

    // staging: wave wv fills 2048B (A) + 2048B (B) per buffer; lane's global source is
    // pre-swizzled so the linear LDS write realizes the chunk swizzle.
    const int sq_  = ((lane & 3) ^ ((lane >> 3) & 3)) * 8;  // swizzled k-chunk (elems)
    const int srL  = wv * 32 + (lane >> 2);                 // row for r=0 (r adds +16)
    // fragment read swizzle
    const int qx   = quad ^ ((l15 >> 1) & 3);

    auto STAGE = [&](int b, int k0) {
        #pragma unroll
        for (int r = 0; r < 2; ++r) {
            const unsigned short* g =
                featb + (size_t)(rowBase + srL + r * 16) * Dsz + k0 + sq_;
            __builtin_amdgcn_global_load_lds((GmemV*)g,
                (LdsV*)(&AB[b][wv * 1024 + r * 512]), 16, 0, 0);
        }
        #pragma unroll
        for (int r = 0; r < 2; ++r) {
            int crow = colBase + srL + r * 16;
            if (crow >= Csz) crow = Csz - 1;  // clamp: stores masked in epilogue
            const unsigned short* g = centb + (size_t)crow * Dsz + k0 + sq_;
            __builtin_amdgcn_global_load_lds((GmemV*)g,
                (LdsV*)(&AB[b][4096 + wv * 1024 + r * 512]), 16, 0, 0);
        }
    };

    STAGE(0, 0);
    if (tid < 128) {
        Fs[tid] = fsq[rowBase + tid];
        Lb[tid] = label[rowBase + tid];
        int c = colBase + tid;
        Cq[tid] = (c < Csz) ? csq[c] : 0.f;
    }

    f32x4 acc[4][4];
    #pragma unroll
    for (int i = 0; i < 4; ++i)
        #pragma unroll
        for (int j = 0; j < 4; ++j)
            acc[i][j] = (f32x4){0.f, 0.f, 0.f, 0.f};

    __syncthreads();  // STAGE(0) drained (vmcnt(0) implicit), all waves ready

    #pragma unroll
    for (int t = 0; t < 8; ++t) {
        const int cur = t & 1;
        if (t < 7) STAGE(cur ^ 1, (t + 1) * BK);   // issue next-tile loads FIRST
        const unsigned short* Ab = &AB[cur][0];
        const unsigned short* Bb = &AB[cur][4096];
        bf16x8 af[4], bfr[4];
        #pragma unroll
        for (int mi = 0; mi < 4; ++mi)
            af[mi] = *(const bf16x8*)(Ab + (wr + mi * 16 + l15) * BK + qx * 8);
        #pragma unroll
        for (int ni = 0; ni < 4; ++ni)
            bfr[ni] = *(const bf16x8*)(Bb + (wc + ni * 16 + l15) * BK + qx * 8);
        #pragma unroll
        for (int mi = 0; mi < 4; ++mi)
            #pragma unroll
            for (int ni = 0; ni < 4; ++ni)
                acc[mi][ni] = __builtin_amdgcn_mfma_f32_16x16x32_bf16(
                    af[mi], bfr[ni], acc[mi][ni], 0, 0, 0);
        __syncthreads();  // drains next-tile vmcnt AFTER ~16 MFMA of cover
    }

    // ---- epilogue: LDS-transpose to full-line float4 stores ----
    float* Ep = (float*)(&AB[0][0]);          // 16 KB = [32][128] f32
    const int rrow = tid >> 5;                // 0..7
    const int rc4  = tid & 31;                // 4-float col block
    float* outL = out;
    float* outM = out + (size_t)Bsz * Csz;

    #pragma unroll
    for (int mi = 0; mi < 4; ++mi) {
        #pragma unroll
        for (int ni = 0; ni < 4; ++ni) {
            #pragma unroll
            for (int r = 0; r < 4; ++r) {
                int row = (wv >> 1) * 16 + quad * 4 + r;        // 0..31
                int col = (wv & 1) * 64 + ni * 16 + l15;        // 0..127
                Ep[row * 128 + (col ^ ((row & 7) << 2))] = acc[mi][ni][r];
            }
        }
        __syncthreads();
        #pragma unroll
        for (int pass = 0; pass < 4; ++pass) {
            int row  = pass * 8 + rrow;                          // 0..31
            int trow = (row >> 4) * 64 + mi * 16 + (row & 15);   // tile row 0..127
            f32x4 v = *(const f32x4*)&Ep[row * 128 + 4 * (rc4 ^ (row & 7))];
            int gc0 = colBase + rc4 * 4;
            if (gc0 < Csz) {
                float fr = Fs[trow];
                int lbv  = Lb[trow];
                float4 cq = *(const float4*)&Cq[rc4 * 4];
                float4 lg, mg;
                lg.x = v[0] - 0.5f * (fr + cq.x);
                lg.y = v[1] - 0.5f * (fr + cq.y);
                lg.z = v[2] - 0.5f * (fr + cq.z);
                lg.w = v[3] - 0.5f * (fr + cq.w);
                mg.x = (gc0 + 0 == lbv) ? lg.x * 1.1f : lg.x;
                mg.y = (gc0 + 1 == lbv) ? lg.y * 1.1f : lg.y;
                mg.z = (gc0 + 2 == lbv) ? lg.z * 1.1f : lg.z;
                mg.w = (gc0 + 3 == lbv) ? lg.w * 1.1f : lg.w;
                size_t off = (size_t)(rowBase + trow) * Csz + gc0;
                *(float4*)(outL + off) = lg;
                *(float4*)(outM + off) = mg;
            }
        }
        if (mi < 3) __syncthreads();   // Ep reuse guard
    }
}

// ================= fallback path (ws too small): previous verified kernels =================
__global__ __launch_bounds__(256) void sqnorm_kernel(
        const float* __restrict__ feat, const float* __restrict__ centers,
        float* __restrict__ ws, float* __restrict__ like_out) {
    if (blockIdx.x == 0 && threadIdx.x == 0) *like_out = 0.f;
    int row  = blockIdx.x * 4 + (threadIdx.x >> 6);
    int lane = threadIdx.x & 63;
    if (row >= Bsz + Csz) return;
    const float* src = (row < Bsz) ? feat + (size_t)row * Dsz
                                   : centers + (size_t)(row - Bsz) * Dsz;
    float4 v = *(const float4*)(src + lane * 4);
    float s = v.x * v.x + v.y * v.y + v.z * v.z + v.w * v.w;
    #pragma unroll
    for (int o = 32; o > 0; o >>= 1) s += __shfl_down(s, o);
    if (lane == 0) ws[row] = s;
}

__global__ __launch_bounds__(256) void lgm_gemm_kernel(
        const float* __restrict__ feat, const float* __restrict__ centers,
        const int* __restrict__ label, const float* __restrict__ fsq,
        const float* __restrict__ csq, float* __restrict__ out) {
    __shared__ unsigned short As[BM * KST];
    __shared__ unsigned short Bs[BN * KST];
    __shared__ float Fs[BM];
    __shared__ float Cq[BN];
    __shared__ int   Lb[BM];

    const int tid     = threadIdx.x;
    const int rowBase = blockIdx.y * BM;
    const int colBase = blockIdx.x * BN;

    if (tid < 128) {
        Fs[tid] = fsq[rowBase + tid];
        Lb[tid] = label[rowBase + tid];
        int c = colBase + tid;
        Cq[tid] = (c < Csz) ? csq[c] : 0.f;
    }

    const int lane = tid & 63;
    const int wv   = tid >> 6;
    const int wr   = (wv >> 1) * 64;
    const int wc   = (wv & 1) * 64;
    const int quad = lane >> 4;
    const int l15  = lane & 15;

    f32x4 acc[4][4];
    #pragma unroll
    for (int i = 0; i < 4; ++i)
        #pragma unroll
        for (int j = 0; j < 4; ++j)
            acc[i][j] = (f32x4){0.f, 0.f, 0.f, 0.f};

    const int sr = tid >> 3;
    const int sf = tid & 7;

    for (int k0 = 0; k0 < Dsz; k0 += BK) {
        __syncthreads();
        #pragma unroll
        for (int rr = 0; rr < BM; rr += 32) {
            int r = sr + rr;
            float4 v = *(const float4*)(feat + (size_t)(rowBase + r) * Dsz + k0 + sf * 4);
            *(uint2*)(As + r * KST + sf * 4) = make_uint2(pack2(v.x, v.y), pack2(v.z, v.w));
        }
        #pragma unroll
        for (int rr = 0; rr < BN; rr += 32) {
            int r = sr + rr;
            int crow = colBase + r;
            if (crow >= Csz) crow = Csz - 1;
            float4 v = *(const float4*)(centers + (size_t)crow * Dsz + k0 + sf * 4);
            *(uint2*)(Bs + r * KST + sf * 4) = make_uint2(pack2(v.x, v.y), pack2(v.z, v.w));
        }
        __syncthreads();

        bf16x8 af[4], bfr[4];
        #pragma unroll
        for (int mi = 0; mi < 4; ++mi)
            af[mi] = *(const bf16x8*)(As + (wr + mi * 16 + l15) * KST + quad * 8);
        #pragma unroll
        for (int ni = 0; ni < 4; ++ni)
            bfr[ni] = *(const bf16x8*)(Bs + (wc + ni * 16 + l15) * KST + quad * 8);
        #pragma unroll
        for (int mi = 0; mi < 4; ++mi)
            #pragma unroll
            for (int ni = 0; ni < 4; ++ni)
                acc[mi][ni] = __builtin_amdgcn_mfma_f32_16x16x32_bf16(
                    af[mi], bfr[ni], acc[mi][ni], 0, 0, 0);
    }

    float* outL = out;
    float* outM = out + (size_t)Bsz * Csz;
    #pragma unroll
    for (int mi = 0; mi < 4; ++mi) {
        const int rT0 = wr + mi * 16 + quad * 4;
        float fr[4]; int lb[4]; int gr[4];
        #pragma unroll
        for (int r = 0; r < 4; ++r) {
            fr[r] = Fs[rT0 + r];
            lb[r] = Lb[rT0 + r];
            gr[r] = rowBase + rT0 + r;
        }
        #pragma unroll
        for (int ni = 0; ni < 4; ++ni) {
            const int cT = wc + ni * 16 + l15;
            const int gc = colBase + cT;
            if (gc >= Csz) continue;
            const float cs = Cq[cT];
            f32x4 a = acc[mi][ni];
            #pragma unroll
            for (int r = 0; r < 4; ++r) {
                float logit = a[r] - 0.5f * (fr[r] + cs);
                float marg  = (gc == lb[r]) ? logit * 1.1f : logit;
                size_t off = (size_t)gr[r] * Csz + gc;
                outL[off] = logit;
                outM[off] = marg;
            }
        }
    }
}

extern "C" void kernel_launch(void* const* d_in, const int* in_sizes, int n_in,
                              void* d_out, int out_size, void* d_ws, size_t ws_size,
                              hipStream_t stream) {
    const float* feat    = (const float*)d_in[0];
    const int*   label   = (const int*)d_in[1];
    const float* centers = (const float*)d_in[2];
    float* out = (float*)d_out;
    float* like_out = out + (size_t)2 * Bsz * Csz;

    const size_t bf_bytes = (size_t)(Bsz + Csz) * Dsz * sizeof(unsigned short); // 7.22 MB
    const size_t ws_need  = bf_bytes + (size_t)(Bsz + Csz) * sizeof(float) + 256;

    if (ws_size >= ws_need) {
        unsigned short* featb = (unsigned short*)d_ws;
        unsigned short* centb = featb + (size_t)Bsz * Dsz;
        float* fsq = (float*)(centb + (size_t)Csz * Dsz);
        float* csq = fsq + Bsz;
        prep_kernel<<<dim3((Bsz + Csz) / 4), 256, 0, stream>>>(
            feat, centers, featb, centb, fsq, csq, like_out);
        like_kernel<<<dim3(Bsz / 4), 256, 0, stream>>>(feat, centers, label, like_out);
        lgm_gemm_bf_kernel<<<dim3(NWG), 256, 0, stream>>>(
            featb, centb, label, fsq, csq, out);
    } else {
        float* fsq = (float*)d_ws;
        float* csq = fsq + Bsz;
        sqnorm_kernel<<<dim3((Bsz + Csz + 3) / 4), 256, 0, stream>>>(feat, centers, fsq, like_out);
        like_kernel<<<dim3(Bsz / 4), 256, 0, stream>>>(feat, centers, label, like_out);
        lgm_gemm_kernel<<<dim3((Csz + BN - 1) / BN, Bsz / BM), 256, 0, stream>>>(
            feat, centers, label, fsq, csq, out);
    }
}

// Round 3
// 443.079 us; speedup vs baseline: 1.0255x; 1.0054x over previous
//
#include <hip/hip_runtime.h>
#include <hip/hip_bf16.h>
#include <stdint.h>

#define Bsz 4096
#define Csz 10000
#define Dsz 256
#define BM 128
#define BN 128
#define BK 32
#define KST 40   // fallback-path LDS row stride (old kernel)

#define NCOLB 79                 // ceil(10000/128)
#define NROWB 32                 // 4096/128
#define NWG   (NCOLB * NROWB)    // 2528 = 8 * 316 exactly -> bijective XCD swizzle
#define CPX   (NWG / 8)          // 316 blocks per XCD chunk

typedef __attribute__((ext_vector_type(8))) __bf16 bf16x8;  // 4 VGPRs, matches mfma builtin
typedef __attribute__((ext_vector_type(4))) float f32x4;

typedef const __attribute__((address_space(1))) void GmemV;
typedef __attribute__((address_space(3))) void LdsV;

__device__ __forceinline__ unsigned int f2bf(float x) {
    unsigned int u = __float_as_uint(x);
    return (u + 0x7fffu + ((u >> 16) & 1u)) >> 16;
}
__device__ __forceinline__ unsigned int pack2(float a, float b) {
    return f2bf(a) | (f2bf(b) << 16);
}

// ---- kernel 1 (fused): bf16 conversion + f_sq/c_sq + likelihood partials ----
// 4 rows/block, 64 lanes/row. Feat rows additionally gather centers[label[row]] (f32)
// and accumulate the likelihood term; saves the separate like_kernel launch and its
// duplicate 4 MB feat read. like_out is pre-zeroed by hipMemsetAsync (launch order).
__global__ __launch_bounds__(256) void prep_kernel(
        const float* __restrict__ feat, const float* __restrict__ centers,
        const int* __restrict__ label,
        unsigned short* __restrict__ featb, unsigned short* __restrict__ centb,
        float* __restrict__ fsq, float* __restrict__ csq, float* __restrict__ like_out) {
    int row  = blockIdx.x * 4 + (threadIdx.x >> 6);
    int lane = threadIdx.x & 63;
    if (row >= Bsz + Csz) return;
    if (row < Bsz) {
        float4 v = *(const float4*)(feat + (size_t)row * Dsz + lane * 4);
        *(uint2*)(featb + (size_t)row * Dsz + lane * 4) =
            make_uint2(pack2(v.x, v.y), pack2(v.z, v.w));
        int lb = label[row];
        float4 c = *(const float4*)(centers + (size_t)lb * Dsz + lane * 4);
        float dx = v.x - c.x, dy = v.y - c.y, dz = v.z - c.z, dw = v.w - c.w;
        float s = v.x * v.x + v.y * v.y + v.z * v.z + v.w * v.w;
        float l = dx * dx + dy * dy + dz * dz + dw * dw;
        #pragma unroll
        for (int o = 32; o > 0; o >>= 1) {
            s += __shfl_down(s, o);
            l += __shfl_down(l, o);
        }
        if (lane == 0) {
            fsq[row] = s;
            atomicAdd(like_out, l * (1.0f / (2.0f * Bsz)));
        }
    } else {
        int r = row - Bsz;
        float4 v = *(const float4*)(centers + (size_t)r * Dsz + lane * 4);
        *(uint2*)(centb + (size_t)r * Dsz + lane * 4) =
            make_uint2(pack2(v.x, v.y), pack2(v.z, v.w));
        float s = v.x * v.x + v.y * v.y + v.z * v.z + v.w * v.w;
        #pragma unroll
        for (int o = 32; o > 0; o >>= 1) s += __shfl_down(s, o);
        if (lane == 0) csq[r] = s;
    }
}

// ---- kernel 2: bf16 GEMM, 2-phase pipelined, swizzled LDS, full-line epilogue ----
// K-loop: 2x16KB double-buffered LDS, global_load_lds width=16 with pre-swizzled
// global source (chunk swizzle q ^= (row>>1)&3) so ds_read_b128 is conflict-free.
// Epilogue: acc -> Ep[32][128] f32 in LDS (ping-pong across the two K-loop buffers,
// 4 barriers total) -> each wave stores 2 rows x 512 B contiguous dwordx4.
__global__ __launch_bounds__(256, 3) void lgm_gemm_bf_kernel(
        const unsigned short* __restrict__ featb, const unsigned short* __restrict__ centb,
        const int* __restrict__ label, const float* __restrict__ fsq,
        const float* __restrict__ csq, float* __restrict__ out) {
    __shared__ __align__(16) unsigned short AB[2][8192];  // [buf][As 4096 | Bs 4096]
    __shared__ float Fs[BM];
    __shared__ float Cq[BN];
    __shared__ int   Lb[BM];

    const int bid = blockIdx.x;
    const int wg  = (bid & 7) * CPX + (bid >> 3);
    const int by  = wg & 31;          // row-block (feat), fastest within XCD chunk
    const int bx  = wg >> 5;          // col-block (centers)
    const int rowBase = by * BM;
    const int colBase = bx * BN;

    const int tid  = threadIdx.x;
    const int lane = tid & 63;
    const int wv   = tid >> 6;
    const int wr   = (wv >> 1) * 64;
    const int wc   = (wv & 1) * 64;
    const int quad = lane >> 4;
    const int l15  = lane & 15;

    const int sq_  = ((lane & 3) ^ ((lane >> 3) & 3)) * 8;  // pre-swizzled k-chunk
    const int srL  = wv * 32 + (lane >> 2);                 // staging row (r adds +16)
    const int qx   = quad ^ ((l15 >> 1) & 3);               // read-side swizzle

    auto STAGE = [&](int b, int k0) {
        #pragma unroll
        for (int r = 0; r < 2; ++r) {
            const unsigned short* g =
                featb + (size_t)(rowBase + srL + r * 16) * Dsz + k0 + sq_;
            __builtin_amdgcn_global_load_lds((GmemV*)g,
                (LdsV*)(&AB[b][wv * 1024 + r * 512]), 16, 0, 0);
        }
        #pragma unroll
        for (int r = 0; r < 2; ++r) {
            int crow = colBase + srL + r * 16;
            if (crow >= Csz) crow = Csz - 1;  // clamp: stores masked in epilogue
            const unsigned short* g = centb + (size_t)crow * Dsz + k0 + sq_;
            __builtin_amdgcn_global_load_lds((GmemV*)g,
                (LdsV*)(&AB[b][4096 + wv * 1024 + r * 512]), 16, 0, 0);
        }
    };

    STAGE(0, 0);
    if (tid < 128) {
        Fs[tid] = fsq[rowBase + tid];
        Lb[tid] = label[rowBase + tid];
        int c = colBase + tid;
        Cq[tid] = (c < Csz) ? csq[c] : 0.f;
    }

    f32x4 acc[4][4];
    #pragma unroll
    for (int i = 0; i < 4; ++i)
        #pragma unroll
        for (int j = 0; j < 4; ++j)
            acc[i][j] = (f32x4){0.f, 0.f, 0.f, 0.f};

    __syncthreads();  // STAGE(0) drained, Fs/Cq/Lb visible

    #pragma unroll
    for (int t = 0; t < 8; ++t) {
        const int cur = t & 1;
        if (t < 7) STAGE(cur ^ 1, (t + 1) * BK);   // issue next-tile loads FIRST
        const unsigned short* Ab = &AB[cur][0];
        const unsigned short* Bb = &AB[cur][4096];
        bf16x8 af[4], bfr[4];
        #pragma unroll
        for (int mi = 0; mi < 4; ++mi)
            af[mi] = *(const bf16x8*)(Ab + (wr + mi * 16 + l15) * BK + qx * 8);
        #pragma unroll
        for (int ni = 0; ni < 4; ++ni)
            bfr[ni] = *(const bf16x8*)(Bb + (wc + ni * 16 + l15) * BK + qx * 8);
        #pragma unroll
        for (int mi = 0; mi < 4; ++mi)
            #pragma unroll
            for (int ni = 0; ni < 4; ++ni)
                acc[mi][ni] = __builtin_amdgcn_mfma_f32_16x16x32_bf16(
                    af[mi], bfr[ni], acc[mi][ni], 0, 0, 0);
        __syncthreads();  // drains next-tile vmcnt AFTER the MFMA cluster
    }

    // ---- epilogue: ping-pong LDS transpose -> full-line float4 stores ----
    const int rrow = tid >> 5;                // 0..7
    const int rc4  = tid & 31;                // 4-float col block
    float* outL = out;
    float* outM = out + (size_t)Bsz * Csz;

    #pragma unroll
    for (int mi = 0; mi < 4; ++mi) {
        float* Ep = (float*)(&AB[mi & 1][0]);  // mi is unrolled -> static index
        #pragma unroll
        for (int ni = 0; ni < 4; ++ni) {
            #pragma unroll
            for (int r = 0; r < 4; ++r) {
                int row = (wv >> 1) * 16 + quad * 4 + r;        // 0..31
                int col = (wv & 1) * 64 + ni * 16 + l15;        // 0..127
                Ep[row * 128 + (col ^ ((row & 7) << 2))] = acc[mi][ni][r];
            }
        }
        __syncthreads();   // Ep[mi&1] complete; also guards reuse two mi's later
        #pragma unroll
        for (int pass = 0; pass < 4; ++pass) {
            int row  = pass * 8 + rrow;                          // 0..31
            int trow = (row >> 4) * 64 + mi * 16 + (row & 15);   // tile row 0..127
            f32x4 v = *(const f32x4*)&Ep[row * 128 + 4 * (rc4 ^ (row & 7))];
            int gc0 = colBase + rc4 * 4;
            if (gc0 < Csz) {
                float fr = Fs[trow];
                int lbv  = Lb[trow];
                float4 cq = *(const float4*)&Cq[rc4 * 4];
                float4 lg, mg;
                lg.x = v[0] - 0.5f * (fr + cq.x);
                lg.y = v[1] - 0.5f * (fr + cq.y);
                lg.z = v[2] - 0.5f * (fr + cq.z);
                lg.w = v[3] - 0.5f * (fr + cq.w);
                mg.x = (gc0 + 0 == lbv) ? lg.x * 1.1f : lg.x;
                mg.y = (gc0 + 1 == lbv) ? lg.y * 1.1f : lg.y;
                mg.z = (gc0 + 2 == lbv) ? lg.z * 1.1f : lg.z;
                mg.w = (gc0 + 3 == lbv) ? lg.w * 1.1f : lg.w;
                size_t off = (size_t)(rowBase + trow) * Csz + gc0;
                *(float4*)(outL + off) = lg;
                *(float4*)(outM + off) = mg;
            }
        }
    }
}

// ================= fallback path (ws too small): previous verified kernels =================
__global__ __launch_bounds__(256) void sqnorm_kernel(
        const float* __restrict__ feat, const float* __restrict__ centers,
        float* __restrict__ ws, float* __restrict__ like_out) {
    if (blockIdx.x == 0 && threadIdx.x == 0) *like_out = 0.f;
    int row  = blockIdx.x * 4 + (threadIdx.x >> 6);
    int lane = threadIdx.x & 63;
    if (row >= Bsz + Csz) return;
    const float* src = (row < Bsz) ? feat + (size_t)row * Dsz
                                   : centers + (size_t)(row - Bsz) * Dsz;
    float4 v = *(const float4*)(src + lane * 4);
    float s = v.x * v.x + v.y * v.y + v.z * v.z + v.w * v.w;
    #pragma unroll
    for (int o = 32; o > 0; o >>= 1) s += __shfl_down(s, o);
    if (lane == 0) ws[row] = s;
}

__global__ __launch_bounds__(256) void like_kernel(
        const float* __restrict__ feat, const float* __restrict__ centers,
        const int* __restrict__ label, float* __restrict__ like_out) {
    int row  = blockIdx.x * 4 + (threadIdx.x >> 6);
    int lane = threadIdx.x & 63;
    int lb = label[row];
    float4 f = *(const float4*)(feat + (size_t)row * Dsz + lane * 4);
    float4 c = *(const float4*)(centers + (size_t)lb * Dsz + lane * 4);
    float dx = f.x - c.x, dy = f.y - c.y, dz = f.z - c.z, dw = f.w - c.w;
    float s = dx * dx + dy * dy + dz * dz + dw * dw;
    #pragma unroll
    for (int o = 32; o > 0; o >>= 1) s += __shfl_down(s, o);
    if (lane == 0) atomicAdd(like_out, s * (1.0f / (2.0f * Bsz)));
}

__global__ __launch_bounds__(256) void lgm_gemm_kernel(
        const float* __restrict__ feat, const float* __restrict__ centers,
        const int* __restrict__ label, const float* __restrict__ fsq,
        const float* __restrict__ csq, float* __restrict__ out) {
    __shared__ unsigned short As[BM * KST];
    __shared__ unsigned short Bs[BN * KST];
    __shared__ float Fs[BM];
    __shared__ float Cq[BN];
    __shared__ int   Lb[BM];

    const int tid     = threadIdx.x;
    const int rowBase = blockIdx.y * BM;
    const int colBase = blockIdx.x * BN;

    if (tid < 128) {
        Fs[tid] = fsq[rowBase + tid];
        Lb[tid] = label[rowBase + tid];
        int c = colBase + tid;
        Cq[tid] = (c < Csz) ? csq[c] : 0.f;
    }

    const int lane = tid & 63;
    const int wv   = tid >> 6;
    const int wr   = (wv >> 1) * 64;
    const int wc   = (wv & 1) * 64;
    const int quad = lane >> 4;
    const int l15  = lane & 15;

    f32x4 acc[4][4];
    #pragma unroll
    for (int i = 0; i < 4; ++i)
        #pragma unroll
        for (int j = 0; j < 4; ++j)
            acc[i][j] = (f32x4){0.f, 0.f, 0.f, 0.f};

    const int sr = tid >> 3;
    const int sf = tid & 7;

    for (int k0 = 0; k0 < Dsz; k0 += BK) {
        __syncthreads();
        #pragma unroll
        for (int rr = 0; rr < BM; rr += 32) {
            int r = sr + rr;
            float4 v = *(const float4*)(feat + (size_t)(rowBase + r) * Dsz + k0 + sf * 4);
            *(uint2*)(As + r * KST + sf * 4) = make_uint2(pack2(v.x, v.y), pack2(v.z, v.w));
        }
        #pragma unroll
        for (int rr = 0; rr < BN; rr += 32) {
            int r = sr + rr;
            int crow = colBase + r;
            if (crow >= Csz) crow = Csz - 1;
            float4 v = *(const float4*)(centers + (size_t)crow * Dsz + k0 + sf * 4);
            *(uint2*)(Bs + r * KST + sf * 4) = make_uint2(pack2(v.x, v.y), pack2(v.z, v.w));
        }
        __syncthreads();

        bf16x8 af[4], bfr[4];
        #pragma unroll
        for (int mi = 0; mi < 4; ++mi)
            af[mi] = *(const bf16x8*)(As + (wr + mi * 16 + l15) * KST + quad * 8);
        #pragma unroll
        for (int ni = 0; ni < 4; ++ni)
            bfr[ni] = *(const bf16x8*)(Bs + (wc + ni * 16 + l15) * KST + quad * 8);
        #pragma unroll
        for (int mi = 0; mi < 4; ++mi)
            #pragma unroll
            for (int ni = 0; ni < 4; ++ni)
                acc[mi][ni] = __builtin_amdgcn_mfma_f32_16x16x32_bf16(
                    af[mi], bfr[ni], acc[mi][ni], 0, 0, 0);
    }

    float* outL = out;
    float* outM = out + (size_t)Bsz * Csz;
    #pragma unroll
    for (int mi = 0; mi < 4; ++mi) {
        const int rT0 = wr + mi * 16 + quad * 4;
        float fr[4]; int lb[4]; int gr[4];
        #pragma unroll
        for (int r = 0; r < 4; ++r) {
            fr[r] = Fs[rT0 + r];
            lb[r] = Lb[rT0 + r];
            gr[r] = rowBase + rT0 + r;
        }
        #pragma unroll
        for (int ni = 0; ni < 4; ++ni) {
            const int cT = wc + ni * 16 + l15;
            const int gc = colBase + cT;
            if (gc >= Csz) continue;
            const float cs = Cq[cT];
            f32x4 a = acc[mi][ni];
            #pragma unroll
            for (int r = 0; r < 4; ++r) {
                float logit = a[r] - 0.5f * (fr[r] + cs);
                float marg  = (gc == lb[r]) ? logit * 1.1f : logit;
                size_t off = (size_t)gr[r] * Csz + gc;
                outL[off] = logit;
                outM[off] = marg;
            }
        }
    }
}

extern "C" void kernel_launch(void* const* d_in, const int* in_sizes, int n_in,
                              void* d_out, int out_size, void* d_ws, size_t ws_size,
                              hipStream_t stream) {
    const float* feat    = (const float*)d_in[0];
    const int*   label   = (const int*)d_in[1];
    const float* centers = (const float*)d_in[2];
    float* out = (float*)d_out;
    float* like_out = out + (size_t)2 * Bsz * Csz;

    const size_t bf_bytes = (size_t)(Bsz + Csz) * Dsz * sizeof(unsigned short); // 7.22 MB
    const size_t ws_need  = bf_bytes + (size_t)(Bsz + Csz) * sizeof(float) + 256;

    if (ws_size >= ws_need) {
        unsigned short* featb = (unsigned short*)d_ws;
        unsigned short* centb = featb + (size_t)Bsz * Dsz;
        float* fsq = (float*)(centb + (size_t)Csz * Dsz);
        float* csq = fsq + Bsz;
        hipMemsetAsync(like_out, 0, sizeof(float), stream);  // graph-capturable memset node
        prep_kernel<<<dim3((Bsz + Csz) / 4), 256, 0, stream>>>(
            feat, centers, label, featb, centb, fsq, csq, like_out);
        lgm_gemm_bf_kernel<<<dim3(NWG), 256, 0, stream>>>(
            featb, centb, label, fsq, csq, out);
    } else {
        float* fsq = (float*)d_ws;
        float* csq = fsq + Bsz;
        sqnorm_kernel<<<dim3((Bsz + Csz + 3) / 4), 256, 0, stream>>>(feat, centers, fsq, like_out);
        like_kernel<<<dim3(Bsz / 4), 256, 0, stream>>>(feat, centers, label, like_out);
        lgm_gemm_kernel<<<dim3((Csz + BN - 1) / BN, Bsz / BM), 256, 0, stream>>>(
            feat, centers, label, fsq, csq, out);
    }
}